// Round 3
// baseline (266.343 us; speedup 1.0000x reference)
//
#include <hip/hip_runtime.h>
#include <math.h>

#define N_NODES 50000
#define N_EDGES 800000
#define D 64

// ---------------- workspace layout (byte offsets, overlapped) ----------------
// x1         @ 0          : 12.8 MB   (layer-1 output)
// x2         @ 12800000   : 12.8 MB   (layer-2 output)
//   counts   @ 12800000   (alias x2; dead before layer-2 writes x2)
//   pos      @ 13000704   (alias x2; dead after scatter)
//   partials @ 13201408   (alias x2; dead after chunk_scan)
// offsets    @ 25600000   : 200 KB    (alive until edge_dot)
// csr_packed @ 25800704   : 6.4 MB    (int2 (src, eid); alive until edge_dot)
// total ~= 32.2 MB
#define X1_OFF   0
#define X2_OFF   12800000
#define CNT_OFF  12800000
#define POS_OFF  13000704
#define PART_OFF 13201408
#define OFF_OFF  25600000
#define CSR_OFF  25800704

__global__ void zero_counts_kernel(int* __restrict__ counts) {
    int i = blockIdx.x * blockDim.x + threadIdx.x;
    if (i < N_NODES) counts[i] = 0;
}

__global__ void hist_kernel(const int* __restrict__ dst, int* __restrict__ counts) {
    int i = blockIdx.x * blockDim.x + threadIdx.x;
    if (i < N_EDGES) atomicAdd(&counts[dst[i]], 1);
}

__global__ void chunk_sum_kernel(const int* __restrict__ counts, int* __restrict__ partials) {
    __shared__ int sdata[256];
    int base = blockIdx.x * 1024;
    int tid = threadIdx.x;
    int sum = 0;
    for (int i = tid; i < 1024; i += 256) {
        int idx = base + i;
        sum += (idx < N_NODES) ? counts[idx] : 0;
    }
    sdata[tid] = sum;
    __syncthreads();
    for (int s = 128; s > 0; s >>= 1) {
        if (tid < s) sdata[tid] += sdata[tid + s];
        __syncthreads();
    }
    if (tid == 0) partials[blockIdx.x] = sdata[0];
}

__global__ void partial_scan_kernel(int* __restrict__ partials, int nchunks) {
    int lane = threadIdx.x;
    int v = (lane < nchunks) ? partials[lane] : 0;
    int orig = v;
    for (int off = 1; off < 64; off <<= 1) {
        int t = __shfl_up(v, off);
        if (lane >= off) v += t;
    }
    if (lane < nchunks) partials[lane] = v - orig;  // exclusive
}

__global__ void chunk_scan_kernel(const int* __restrict__ counts,
                                  const int* __restrict__ partials,
                                  int* __restrict__ offsets,
                                  int* __restrict__ pos) {
    __shared__ int sdata[256];
    int base = blockIdx.x * 1024;
    int tid = threadIdx.x;
    int v[4];
    int s = 0;
    for (int j = 0; j < 4; ++j) {
        int idx = base + tid * 4 + j;
        v[j] = (idx < N_NODES) ? counts[idx] : 0;
        s += v[j];
    }
    sdata[tid] = s;
    __syncthreads();
    for (int off = 1; off < 256; off <<= 1) {
        int t = (tid >= off) ? sdata[tid - off] : 0;
        __syncthreads();
        sdata[tid] += t;
        __syncthreads();
    }
    int excl = sdata[tid] - s + partials[blockIdx.x];
    for (int j = 0; j < 4; ++j) {
        int idx = base + tid * 4 + j;
        if (idx < N_NODES) {
            offsets[idx] = excl;
            pos[idx] = excl;
        }
        excl += v[j];
        if (idx == N_NODES - 1) offsets[N_NODES] = excl;
    }
}

__global__ void scatter_kernel(const int* __restrict__ src, const int* __restrict__ dst,
                               int* __restrict__ pos, int2* __restrict__ csr_packed) {
    int i = blockIdx.x * blockDim.x + threadIdx.x;
    if (i < N_EDGES) {
        int slot = atomicAdd(&pos[dst[i]], 1);
        int2 v;
        v.x = src[i];
        v.y = i;
        csr_packed[slot] = v;
    }
}

// Fused SAGE layer, v3.
// Block = 256 = 4 independent waves, 16 nodes per wave, NO barriers.
// Gather: all 64 lanes work one node at a time: eq = lane>>4 picks every-4th
// edge, sub = lane&15 picks the float4 feature quarter; unroll 2 -> 8 rows
// in flight per wave; cross-eq reduce via shfl_xor(16/32).
// GEMM: W read directly from global (L1-resident 32 KB broadcast pattern),
// h rows from per-wave LDS (17-float4 stride, conflict-free), self rows from
// global (L1-hot block region). LDS = 17408 B -> ~8 blocks/CU (VGPR-capped).
__global__ __launch_bounds__(256) void sage_layer_kernel(
    const float* __restrict__ x_in,
    const int* __restrict__ offsets,
    const int* __restrict__ csr_src2,   // int2 stream, stride-2 ints; [2*t] = src
    const float* __restrict__ W_self, const float* __restrict__ W_neigh,
    const float* __restrict__ bias,
    float* __restrict__ x_out) {
    __shared__ float4 hL[4][16 * 17];

    const int tid = threadIdx.x;
    const int w = tid >> 6;
    const int lane = tid & 63;
    const int eq = lane >> 4;
    const int sub = lane & 15;
    const int g = eq;
    const int nb = blockIdx.x * 64 + w * 16;  // first node of this wave

    const float4* x4 = (const float4*)x_in;

    // preload the wave's 17 CSR offsets (lane-indexed, broadcast via shfl)
    int off_l = 0;
    {
        int idx = nb + lane;
        if (idx > N_NODES) idx = N_NODES;
        if (lane < 17) off_l = offsets[idx];
    }

    // ---- gather: 16 nodes sequential, 64 lanes each ----
    for (int i = 0; i < 16; ++i) {
        int e0 = __shfl(off_l, i);
        int e1 = __shfl(off_l, i + 1);
        float4 acc0 = make_float4(0.f, 0.f, 0.f, 0.f);
        float4 acc1 = make_float4(0.f, 0.f, 0.f, 0.f);
        int t = e0 + eq;
        for (; t + 4 < e1; t += 8) {
            int s0 = csr_src2[2 * t];
            int s1 = csr_src2[2 * (t + 4)];
            float4 r0 = x4[s0 * 16 + sub];
            float4 r1 = x4[s1 * 16 + sub];
            acc0.x += r0.x; acc0.y += r0.y; acc0.z += r0.z; acc0.w += r0.w;
            acc1.x += r1.x; acc1.y += r1.y; acc1.z += r1.z; acc1.w += r1.w;
        }
        if (t < e1) {
            int s = csr_src2[2 * t];
            float4 r = x4[s * 16 + sub];
            acc0.x += r.x; acc0.y += r.y; acc0.z += r.z; acc0.w += r.w;
        }
        float4 acc;
        acc.x = acc0.x + acc1.x;
        acc.y = acc0.y + acc1.y;
        acc.z = acc0.z + acc1.z;
        acc.w = acc0.w + acc1.w;
        acc.x += __shfl_xor(acc.x, 16); acc.x += __shfl_xor(acc.x, 32);
        acc.y += __shfl_xor(acc.y, 16); acc.y += __shfl_xor(acc.y, 32);
        acc.z += __shfl_xor(acc.z, 16); acc.z += __shfl_xor(acc.z, 32);
        acc.w += __shfl_xor(acc.w, 16); acc.w += __shfl_xor(acc.w, 32);
        float invd = 1.0f / fmaxf((float)(e1 - e0), 1.0f);
        if (eq == 0) {
            float4 hv;
            hv.x = acc.x * invd; hv.y = acc.y * invd;
            hv.z = acc.z * invd; hv.w = acc.w * invd;
            hL[w][i * 17 + sub] = hv;
        }
    }
    // hL written and read by the same wave -> ordered via lgkmcnt (no barrier)

    // ---- GEMM: out[node] = relu(a @ Ws + h @ Wn + b) ----
    const float4* Wsg = (const float4*)W_self;
    const float4* Wng = (const float4*)W_neigh;
    const float4 b4 = ((const float4*)bias)[sub];
    float4 accs0 = b4, accs1 = b4, accs2 = b4, accs3 = b4;

    int n0 = nb + 0 * 4 + g; if (n0 > N_NODES - 1) n0 = N_NODES - 1;
    int n1 = nb + 1 * 4 + g; if (n1 > N_NODES - 1) n1 = N_NODES - 1;
    int n2 = nb + 2 * 4 + g; if (n2 > N_NODES - 1) n2 = N_NODES - 1;
    int n3 = nb + 3 * 4 + g; if (n3 > N_NODES - 1) n3 = N_NODES - 1;
    const float4* arow0 = x4 + n0 * 16;
    const float4* arow1 = x4 + n1 * 16;
    const float4* arow2 = x4 + n2 * 16;
    const float4* arow3 = x4 + n3 * 16;
    const float4* hrow0 = &hL[w][(0 * 4 + g) * 17];
    const float4* hrow1 = &hL[w][(1 * 4 + g) * 17];
    const float4* hrow2 = &hL[w][(2 * 4 + g) * 17];
    const float4* hrow3 = &hL[w][(3 * 4 + g) * 17];

    for (int kk = 0; kk < 16; ++kk) {
        float4 ws0 = Wsg[(kk * 4 + 0) * 16 + sub];
        float4 ws1 = Wsg[(kk * 4 + 1) * 16 + sub];
        float4 ws2 = Wsg[(kk * 4 + 2) * 16 + sub];
        float4 ws3 = Wsg[(kk * 4 + 3) * 16 + sub];
        float4 wn0 = Wng[(kk * 4 + 0) * 16 + sub];
        float4 wn1 = Wng[(kk * 4 + 1) * 16 + sub];
        float4 wn2 = Wng[(kk * 4 + 2) * 16 + sub];
        float4 wn3 = Wng[(kk * 4 + 3) * 16 + sub];

#define SAGE_FMA(ACC, A4, H4)                                                   \
        {                                                                       \
            float4 a4 = (A4); float4 h4 = (H4);                                 \
            ACC.x += a4.x * ws0.x + a4.y * ws1.x + a4.z * ws2.x + a4.w * ws3.x  \
                   + h4.x * wn0.x + h4.y * wn1.x + h4.z * wn2.x + h4.w * wn3.x; \
            ACC.y += a4.x * ws0.y + a4.y * ws1.y + a4.z * ws2.y + a4.w * ws3.y  \
                   + h4.x * wn0.y + h4.y * wn1.y + h4.z * wn2.y + h4.w * wn3.y; \
            ACC.z += a4.x * ws0.z + a4.y * ws1.z + a4.z * ws2.z + a4.w * ws3.z  \
                   + h4.x * wn0.z + h4.y * wn1.z + h4.z * wn2.z + h4.w * wn3.z; \
            ACC.w += a4.x * ws0.w + a4.y * ws1.w + a4.z * ws2.w + a4.w * ws3.w  \
                   + h4.x * wn0.w + h4.y * wn1.w + h4.z * wn2.w + h4.w * wn3.w; \
        }
        SAGE_FMA(accs0, arow0[kk], hrow0[kk]);
        SAGE_FMA(accs1, arow1[kk], hrow1[kk]);
        SAGE_FMA(accs2, arow2[kk], hrow2[kk]);
        SAGE_FMA(accs3, arow3[kk], hrow3[kk]);
#undef SAGE_FMA
    }

    float4* out4 = (float4*)x_out;
#define SAGE_STORE(M, ACC)                                                      \
    {                                                                           \
        int node = nb + (M) * 4 + g;                                            \
        if (node < N_NODES) {                                                   \
            float4 r;                                                           \
            r.x = fmaxf(ACC.x, 0.f); r.y = fmaxf(ACC.y, 0.f);                   \
            r.z = fmaxf(ACC.z, 0.f); r.w = fmaxf(ACC.w, 0.f);                   \
            out4[node * 16 + sub] = r;                                          \
        }                                                                       \
    }
    SAGE_STORE(0, accs0);
    SAGE_STORE(1, accs1);
    SAGE_STORE(2, accs2);
    SAGE_STORE(3, accs3);
#undef SAGE_STORE
}

// Edge dot in CSR (dst-sorted) order: dst row loaded ONCE per node, src rows
// random. 1 wave per node: eq = lane>>4 -> 4 edges in parallel, unroll 2 -> 8
// src rows in flight. Output scattered via stored edge id.
__global__ __launch_bounds__(256) void edge_dot_csr_kernel(
    const float* __restrict__ x,
    const int* __restrict__ offsets,
    const int2* __restrict__ csr_packed,
    float* __restrict__ out) {
    const int tid = threadIdx.x;
    const int w = tid >> 6;
    const int lane = tid & 63;
    const int eq = lane >> 4;
    const int sub = lane & 15;
    const int node = blockIdx.x * 4 + w;
    if (node >= N_NODES) return;

    const float4* x4 = (const float4*)x;
    const float4 bq = x4[node * 16 + sub];
    const int e0 = offsets[node];
    const int e1 = offsets[node + 1];

#define EDGE_EMIT(C, A)                                                         \
    {                                                                           \
        float p = (A).x * bq.x + (A).y * bq.y + (A).z * bq.z + (A).w * bq.w;    \
        p += __shfl_xor(p, 1);                                                  \
        p += __shfl_xor(p, 2);                                                  \
        p += __shfl_xor(p, 4);                                                  \
        p += __shfl_xor(p, 8);                                                  \
        if (sub == 0) {                                                         \
            float s1 = 1.f / (1.f + __expf(-p));                                \
            out[(C).y] = 1.f / (1.f + __expf(-s1));                             \
        }                                                                       \
    }

    int t = e0 + eq;
    for (; t + 4 < e1; t += 8) {
        int2 c0 = csr_packed[t];
        int2 c1 = csr_packed[t + 4];
        float4 a0 = x4[c0.x * 16 + sub];
        float4 a1 = x4[c1.x * 16 + sub];
        EDGE_EMIT(c0, a0);
        EDGE_EMIT(c1, a1);
    }
    if (t < e1) {
        int2 c = csr_packed[t];
        float4 a = x4[c.x * 16 + sub];
        EDGE_EMIT(c, a);
    }
#undef EDGE_EMIT
}

extern "C" void kernel_launch(void* const* d_in, const int* in_sizes, int n_in,
                              void* d_out, int out_size, void* d_ws, size_t ws_size,
                              hipStream_t stream) {
    const float* feats = (const float*)d_in[0];
    const int* src = (const int*)d_in[1];
    const int* dst = (const int*)d_in[2];
    const float* Ws1 = (const float*)d_in[3];
    const float* Wn1 = (const float*)d_in[4];
    const float* b1 = (const float*)d_in[5];
    const float* Ws2 = (const float*)d_in[6];
    const float* Wn2 = (const float*)d_in[7];
    const float* b2 = (const float*)d_in[8];
    float* out = (float*)d_out;

    char* ws = (char*)d_ws;
    float* x1       = (float*)(ws + X1_OFF);
    float* x2       = (float*)(ws + X2_OFF);
    int* counts     = (int*)(ws + CNT_OFF);
    int* pos        = (int*)(ws + POS_OFF);
    int* partials   = (int*)(ws + PART_OFF);
    int* offsets    = (int*)(ws + OFF_OFF);
    int2* csr       = (int2*)(ws + CSR_OFF);

    zero_counts_kernel<<<(N_NODES + 255) / 256, 256, 0, stream>>>(counts);
    hist_kernel<<<(N_EDGES + 255) / 256, 256, 0, stream>>>(dst, counts);
    chunk_sum_kernel<<<49, 256, 0, stream>>>(counts, partials);
    partial_scan_kernel<<<1, 64, 0, stream>>>(partials, 49);
    chunk_scan_kernel<<<49, 256, 0, stream>>>(counts, partials, offsets, pos);
    scatter_kernel<<<(N_EDGES + 255) / 256, 256, 0, stream>>>(src, dst, pos, csr);

    const int sage_grid = (N_NODES + 63) / 64;  // 782
    sage_layer_kernel<<<sage_grid, 256, 0, stream>>>(feats, offsets, (const int*)csr, Ws1, Wn1, b1, x1);
    sage_layer_kernel<<<sage_grid, 256, 0, stream>>>(x1, offsets, (const int*)csr, Ws2, Wn2, b2, x2);

    edge_dot_csr_kernel<<<(N_NODES + 3) / 4, 256, 0, stream>>>(x2, offsets, csr, out);
}